// Round 3
// baseline (163.719 us; speedup 1.0000x reference)
//
#include <hip/hip_runtime.h>

#define N_NODES 100000
#define N_EDGES 1600000
#define VOCAB   1000
#define EMB_DIM 64
#define OUT_DIM 32

#define BKT_BITS 9
#define BKT_SIZE 512
#define NBKT ((N_NODES + BKT_SIZE - 1) / BKT_SIZE)     // 196
#define CAP  12288                                     // per-bucket capacity (avg 8163)
#define NSB  512                                       // scatter blocks
#define CHUNK (N_EDGES / NSB)                          // 3125 exact

#define NBC 256   // fallback streaming-coeff blocks
#define TBC 512

__device__ __forceinline__ void fatomic_add(float* p, float v) {
    unsafeAtomicAdd(p, v);   // ds_add_f32 / global_atomic_add_f32
}

// ---- K1: cursors[0..NBKT-1] col-buckets, [NBKT..2*NBKT-1] row-buckets -----
__global__ void k_init(int* __restrict__ cursors) {
    int i = blockIdx.x * blockDim.x + threadIdx.x;
    if (i < 2 * NBKT) cursors[i] = (i < NBKT ? i : i - NBKT) * CAP;
}

// ---- K2: one pass over edges -> two bucketed record sets ------------------
// colrec: (local_col, w)  keyed by col>>9   -> degree accumulation
// rowrec: (col | lrow<<17, w) keyed by row>>9 -> S_out accumulation
__global__ void __launch_bounds__(256) k_scatter2(
        const int* __restrict__ row, const int* __restrict__ col,
        const float* __restrict__ w, int* __restrict__ cursors,
        uint2* __restrict__ colrec, uint2* __restrict__ rowrec) {
    __shared__ int cC[NBKT], cR[NBKT], bC[NBKT], bR[NBKT];
    for (int i = threadIdx.x; i < NBKT; i += 256) { cC[i] = 0; cR[i] = 0; }
    __syncthreads();
    const int e0 = blockIdx.x * CHUNK;
    for (int i = threadIdx.x; i < CHUNK; i += 256) {
        atomicAdd(&cC[col[e0 + i] >> BKT_BITS], 1);
        atomicAdd(&cR[row[e0 + i] >> BKT_BITS], 1);
    }
    __syncthreads();
    for (int i = threadIdx.x; i < NBKT; i += 256) {
        bC[i] = atomicAdd(&cursors[i], cC[i]);
        bR[i] = atomicAdd(&cursors[NBKT + i], cR[i]);
        cC[i] = 0; cR[i] = 0;
    }
    __syncthreads();
    for (int i = threadIdx.x; i < CHUNK; i += 256) {
        int c = col[e0 + i];                       // L2-warm second read
        int r = row[e0 + i];
        unsigned ww = __float_as_uint(w[e0 + i]);
        int pb = c >> BKT_BITS;
        colrec[bC[pb] + atomicAdd(&cC[pb], 1)] =
            make_uint2((unsigned)(c & (BKT_SIZE - 1)), ww);
        int rb = r >> BKT_BITS;
        rowrec[bR[rb] + atomicAdd(&cR[rb], 1)] =
            make_uint2((unsigned)c | ((unsigned)(r & (BKT_SIZE - 1)) << 17), ww);
    }
}

// ---- K3: per col-bucket: dis[n] = rsqrt(1 + sum_w) ------------------------
__global__ void __launch_bounds__(256) k_bucket_dis(
        const uint2* __restrict__ colrec, const int* __restrict__ cursors,
        float* __restrict__ dis) {
    __shared__ float acc[BKT_SIZE];
    const int b = blockIdx.x;
    for (int i = threadIdx.x; i < BKT_SIZE; i += 256) acc[i] = 0.0f;
    __syncthreads();
    const int base = b * CAP;
    const int cnt = cursors[b] - base;
    for (int i = threadIdx.x; i < cnt; i += 256) {
        uint2 r = colrec[base + i];
        fatomic_add(&acc[r.x], __uint_as_float(r.y));
    }
    __syncthreads();
    const int n0 = b << BKT_BITS;
    for (int i = threadIdx.x; i < BKT_SIZE && n0 + i < N_NODES; i += 256)
        dis[n0 + i] = __frsqrt_rn(1.0f + acc[i]);
}

// ---- K4: per row-bucket: S_out in LDS, then vocab histogram ---------------
// coeff contribution of node n:  dis[n] * (S_out[n] + dis[n])
__global__ void __launch_bounds__(512) k_bucket_coeff(
        const uint2* __restrict__ rowrec, const int* __restrict__ cursors,
        const float* __restrict__ dis, const int* __restrict__ node_seq,
        float* __restrict__ gcoeff) {
    __shared__ float sacc[BKT_SIZE];
    __shared__ float lc[VOCAB];
    const int b = blockIdx.x;
    for (int i = threadIdx.x; i < BKT_SIZE; i += 512) sacc[i] = 0.0f;
    for (int i = threadIdx.x; i < VOCAB; i += 512) lc[i] = 0.0f;
    __syncthreads();
    const int base = b * CAP;
    const int cnt = cursors[NBKT + b] - base;
    for (int i = threadIdx.x; i < cnt; i += 512) {
        uint2 rec = rowrec[base + i];
        int c  = rec.x & 0x1FFFF;
        int lr = rec.x >> 17;
        fatomic_add(&sacc[lr], __uint_as_float(rec.y) * dis[c]);  // 1 gather/edge
    }
    __syncthreads();
    const int n0 = b << BKT_BITS;
    for (int i = threadIdx.x; i < BKT_SIZE; i += 512) {
        int n = n0 + i;
        if (n < N_NODES) {
            float d = dis[n];                       // linear
            fatomic_add(&lc[node_seq[n]], d * (sacc[i] + d));  // linear seq read
        }
    }
    __syncthreads();
    for (int i = threadIdx.x; i < VOCAB; i += 512)
        gcoeff[b * VOCAB + i] = lc[i];
}

// ===== fallback path (ws too small): direct atomics ========================
__global__ void k_init_deg(float* __restrict__ deg) {
    int i = blockIdx.x * blockDim.x + threadIdx.x;
    if (i < N_NODES) deg[i] = 1.0f;
}
__global__ void k_deg(const int* __restrict__ col, const float* __restrict__ w,
                      float* __restrict__ deg) {
    int i = blockIdx.x * blockDim.x + threadIdx.x;
    if (i < N_EDGES) fatomic_add(&deg[col[i]], w[i]);
}
__global__ void k_dis(float* __restrict__ deg) {
    int i = blockIdx.x * blockDim.x + threadIdx.x;
    if (i < N_NODES) deg[i] = __frsqrt_rn(deg[i]);
}
__global__ void __launch_bounds__(TBC) k_coeff_stream(
        const int* __restrict__ row, const int* __restrict__ col,
        const float* __restrict__ w, const float* __restrict__ dis,
        const int* __restrict__ node_seq, float* __restrict__ gcoeff) {
    __shared__ float lc[VOCAB];
    for (int i = threadIdx.x; i < VOCAB; i += TBC) lc[i] = 0.0f;
    __syncthreads();
    const int total = N_EDGES + N_NODES;
    const int stride = NBC * TBC;
    for (int i = blockIdx.x * TBC + threadIdx.x; i < total; i += stride) {
        if (i < N_EDGES) {
            int r = row[i];
            fatomic_add(&lc[node_seq[r]], dis[r] * w[i] * dis[col[i]]);
        } else {
            int n = i - N_EDGES;
            float d = dis[n];
            fatomic_add(&lc[node_seq[n]], d * d);
        }
    }
    __syncthreads();
    for (int i = threadIdx.x; i < VOCAB; i += TBC)
        gcoeff[blockIdx.x * VOCAB + i] = lc[i];
}

// ---- reduce npart partials, one wave per vocab slot -----------------------
__global__ void __launch_bounds__(256) k_reduce(
        const float* __restrict__ gcoeff, float* __restrict__ coeff, int npart) {
    int g = blockIdx.x * 256 + threadIdx.x;
    int v = g >> 6;
    int l = g & 63;
    if (v >= VOCAB) return;
    float s = 0.0f;
    for (int p = l; p < npart; p += 64) s += gcoeff[p * VOCAB + v];
    for (int off = 32; off > 0; off >>= 1) s += __shfl_down(s, off, 64);
    if (l == 0) coeff[v] = s;
}

// ---- out[d] = (sum_v coeff[v]*(emb@W)[v,d])/N + b[d] ----------------------
__global__ void __launch_bounds__(1024) k_final(
        const float* __restrict__ coeff, const float* __restrict__ emb,
        const float* __restrict__ W, const float* __restrict__ bias,
        float* __restrict__ out) {
    __shared__ float lc[VOCAB];
    __shared__ float tk[16 * 64];
    int t = threadIdx.x;
    for (int v = t; v < VOCAB; v += 1024) lc[v] = coeff[v];
    __syncthreads();

    int k = t & 63;
    int g = t >> 6;
    float p = 0.0f;
    for (int v = g; v < VOCAB; v += 16) p += lc[v] * emb[v * EMB_DIM + k];
    tk[g * 64 + k] = p;
    __syncthreads();

    if (t < 64) {
        float s = 0.0f;
        for (int gg = 0; gg < 16; ++gg) s += tk[gg * 64 + t];
        tk[t] = s;
    }
    __syncthreads();

    if (t < OUT_DIM) {
        float s = 0.0f;
        for (int kk = 0; kk < EMB_DIM; ++kk) s += tk[kk] * W[kk * OUT_DIM + t];
        out[t] = s * (1.0f / (float)N_NODES) + bias[t];
    }
}

extern "C" void kernel_launch(void* const* d_in, const int* in_sizes, int n_in,
                              void* d_out, int out_size, void* d_ws, size_t ws_size,
                              hipStream_t stream) {
    const int*   node_seq = (const int*)  d_in[0];
    const int*   eidx     = (const int*)  d_in[1];   // [2, E] flat
    const float* ew       = (const float*)d_in[2];
    const float* emb      = (const float*)d_in[3];
    const float* W        = (const float*)d_in[4];
    const float* b        = (const float*)d_in[5];
    float*       out      = (float*)d_out;

    const int* row = eidx;
    const int* col = eidx + N_EDGES;

    char* wsb = (char*)d_ws;
    const size_t REC_BYTES = (size_t)NBKT * CAP * sizeof(uint2);  // ~19.3 MB each
    const size_t need = 2 * REC_BYTES + 4096 + (size_t)N_NODES * 4
                      + (size_t)NBKT * VOCAB * 4 + VOCAB * 4 + 4096;

    if (ws_size >= need) {
        uint2* colrec  = (uint2*)wsb;
        uint2* rowrec  = (uint2*)(wsb + REC_BYTES);
        int*   cursors = (int*)(wsb + 2 * REC_BYTES);
        float* dis     = (float*)(wsb + 2 * REC_BYTES + 4096);
        float* gcoeff  = dis + N_NODES;
        float* coeff   = gcoeff + (size_t)NBKT * VOCAB;

        k_init<<<2, 256, 0, stream>>>(cursors);
        k_scatter2<<<NSB, 256, 0, stream>>>(row, col, ew, cursors, colrec, rowrec);
        k_bucket_dis<<<NBKT, 256, 0, stream>>>(colrec, cursors, dis);
        k_bucket_coeff<<<NBKT, 512, 0, stream>>>(rowrec, cursors, dis, node_seq, gcoeff);
        k_reduce<<<(VOCAB * 64 + 255) / 256, 256, 0, stream>>>(gcoeff, coeff, NBKT);
        k_final<<<1, 1024, 0, stream>>>(coeff, emb, W, b, out);
    } else {
        float* dis    = (float*)wsb;                  // doubles as deg
        float* gcoeff = dis + N_NODES;
        float* coeff  = gcoeff + (size_t)NBC * VOCAB;

        k_init_deg<<<(N_NODES + 255) / 256, 256, 0, stream>>>(dis);
        k_deg<<<(N_EDGES + 255) / 256, 256, 0, stream>>>(col, ew, dis);
        k_dis<<<(N_NODES + 255) / 256, 256, 0, stream>>>(dis);
        k_coeff_stream<<<NBC, TBC, 0, stream>>>(row, col, ew, dis, node_seq, gcoeff);
        k_reduce<<<(VOCAB * 64 + 255) / 256, 256, 0, stream>>>(gcoeff, coeff, NBC);
        k_final<<<1, 1024, 0, stream>>>(coeff, emb, W, b, out);
    }
}

// Round 4
// 145.579 us; speedup vs baseline: 1.1246x; 1.1246x over previous
//
#include <hip/hip_runtime.h>

#define N_NODES 100000
#define N_EDGES 1600000
#define VOCAB   1000
#define EMB_DIM 64
#define OUT_DIM 32

#define BKT_BITS 9
#define BKT_SIZE 512
#define NBKT ((N_NODES + BKT_SIZE - 1) / BKT_SIZE)     // 196
#define CAP  12288                                     // per-bucket capacity (avg 8192, 45 sigma headroom)
#define NSB  512                                       // scatter blocks
#define CHUNK (N_EDGES / NSB)                          // 3125 exact

#define NBC 256   // fallback streaming-coeff blocks
#define TBC 512

__device__ __forceinline__ void fatomic_add(float* p, float v) {
    unsafeAtomicAdd(p, v);   // ds_add_f32 / global_atomic_add_f32
}

// ---- K1: cursors[b] = b*CAP ----------------------------------------------
__global__ void k_init(int* __restrict__ cursors) {
    int i = blockIdx.x * blockDim.x + threadIdx.x;
    if (i < NBKT) cursors[i] = i * CAP;
}

// ---- K2: LDS counting-sort scatter; coalesced segment writes --------------
// record: x = (row<<9) | local_col, y = w_bits ; keyed by col>>9
__global__ void __launch_bounds__(256) k_scatter(
        const int* __restrict__ row, const int* __restrict__ col,
        const float* __restrict__ w, int* __restrict__ cursors,
        uint2* __restrict__ recs) {
    __shared__ uint2 stage[CHUNK];
    __shared__ unsigned char seg[CHUNK];
    __shared__ int cnt[NBKT], lofs[NBKT], gbase[NBKT];
    __shared__ int sc[256];
    const int tid = threadIdx.x;
    const int e0 = blockIdx.x * CHUNK;

    for (int i = tid; i < NBKT; i += 256) cnt[i] = 0;
    __syncthreads();
    // count
    for (int i = tid; i < CHUNK; i += 256)
        atomicAdd(&cnt[col[e0 + i] >> BKT_BITS], 1);
    __syncthreads();
    // inclusive scan (Hillis-Steele over 256-padded array)
    sc[tid] = (tid < NBKT) ? cnt[tid] : 0;
    __syncthreads();
    for (int d = 1; d < 256; d <<= 1) {
        int v = (tid >= d) ? sc[tid - d] : 0;
        __syncthreads();
        sc[tid] += v;
        __syncthreads();
    }
    if (tid < NBKT) {
        lofs[tid]  = sc[tid] - cnt[tid];                 // exclusive prefix
        gbase[tid] = atomicAdd(&cursors[tid], cnt[tid]); // reserve global slice
        cnt[tid]   = 0;                                  // reuse as running cursor
    }
    __syncthreads();
    // reorder into LDS stage, sorted by bucket
    for (int i = tid; i < CHUNK; i += 256) {
        int c = col[e0 + i];                             // L1/L2-warm second read
        int r = row[e0 + i];
        int b = c >> BKT_BITS;
        int p = lofs[b] + atomicAdd(&cnt[b], 1);
        stage[p] = make_uint2(((unsigned)r << BKT_BITS) | (unsigned)(c & (BKT_SIZE - 1)),
                              __float_as_uint(w[e0 + i]));
        seg[p] = (unsigned char)b;
    }
    __syncthreads();
    // coalesced writeout: consecutive i -> consecutive dst within each segment
    for (int i = tid; i < CHUNK; i += 256) {
        int b = seg[i];
        recs[gbase[b] + (i - lofs[b])] = stage[i];
    }
}

// ---- K3: per bucket: acc = sum w; disseq[n] = {rsqrt(1+acc), node_seq[n]} -
__global__ void __launch_bounds__(256) k_dis(
        const uint2* __restrict__ recs, const int* __restrict__ cursors,
        const int* __restrict__ node_seq, uint2* __restrict__ disseq) {
    __shared__ float acc[BKT_SIZE];
    const int b = blockIdx.x;
    for (int i = threadIdx.x; i < BKT_SIZE; i += 256) acc[i] = 0.0f;
    __syncthreads();
    const int base = b * CAP;
    const int cnt = cursors[b] - base;
    for (int i = threadIdx.x; i < cnt; i += 256) {
        uint2 r = recs[base + i];
        fatomic_add(&acc[r.x & (BKT_SIZE - 1)], __uint_as_float(r.y));
    }
    __syncthreads();
    const int n0 = b << BKT_BITS;
    for (int i = threadIdx.x; i < BKT_SIZE && n0 + i < N_NODES; i += 256)
        disseq[n0 + i] = make_uint2(__float_as_uint(__frsqrt_rn(1.0f + acc[i])),
                                    (unsigned)node_seq[n0 + i]);
}

// ---- K4: per bucket: vocab histogram; one 8B gather per edge --------------
__global__ void __launch_bounds__(512) k_coeff(
        const uint2* __restrict__ recs, const int* __restrict__ cursors,
        const uint2* __restrict__ disseq, float* __restrict__ gcoeff) {
    __shared__ float dloc[BKT_SIZE];
    __shared__ float lc[VOCAB];
    const int b = blockIdx.x;
    const int n0 = b << BKT_BITS;
    for (int i = threadIdx.x; i < VOCAB; i += 512) lc[i] = 0.0f;
    if (threadIdx.x < BKT_SIZE) {
        int n = n0 + threadIdx.x;
        dloc[threadIdx.x] = (n < N_NODES) ? __uint_as_float(disseq[n].x) : 0.0f;
    }
    __syncthreads();
    const int base = b * CAP;
    const int cnt = cursors[b] - base;
    for (int i = threadIdx.x; i < cnt; i += 512) {
        uint2 rec = recs[base + i];
        int lcol = rec.x & (BKT_SIZE - 1);
        int r    = rec.x >> BKT_BITS;
        uint2 ds = disseq[r];                            // single 8B L2 gather
        float norm = __uint_as_float(ds.x) * __uint_as_float(rec.y) * dloc[lcol];
        fatomic_add(&lc[ds.y], norm);
    }
    // self loops for this bucket's nodes (linear reads)
    if (threadIdx.x < BKT_SIZE) {
        int n = n0 + threadIdx.x;
        if (n < N_NODES) {
            uint2 ds = disseq[n];
            float d = __uint_as_float(ds.x);
            fatomic_add(&lc[ds.y], d * d);
        }
    }
    __syncthreads();
    for (int i = threadIdx.x; i < VOCAB; i += 512)
        gcoeff[b * VOCAB + i] = lc[i];
}

// ===== fallback path (ws too small): direct atomics ========================
__global__ void k_init_deg(float* __restrict__ deg) {
    int i = blockIdx.x * blockDim.x + threadIdx.x;
    if (i < N_NODES) deg[i] = 1.0f;
}
__global__ void k_deg(const int* __restrict__ col, const float* __restrict__ w,
                      float* __restrict__ deg) {
    int i = blockIdx.x * blockDim.x + threadIdx.x;
    if (i < N_EDGES) fatomic_add(&deg[col[i]], w[i]);
}
__global__ void k_dis_fb(float* __restrict__ deg) {
    int i = blockIdx.x * blockDim.x + threadIdx.x;
    if (i < N_NODES) deg[i] = __frsqrt_rn(deg[i]);
}
__global__ void __launch_bounds__(TBC) k_coeff_stream(
        const int* __restrict__ row, const int* __restrict__ col,
        const float* __restrict__ w, const float* __restrict__ dis,
        const int* __restrict__ node_seq, float* __restrict__ gcoeff) {
    __shared__ float lc[VOCAB];
    for (int i = threadIdx.x; i < VOCAB; i += TBC) lc[i] = 0.0f;
    __syncthreads();
    const int total = N_EDGES + N_NODES;
    const int stride = NBC * TBC;
    for (int i = blockIdx.x * TBC + threadIdx.x; i < total; i += stride) {
        if (i < N_EDGES) {
            int r = row[i];
            fatomic_add(&lc[node_seq[r]], dis[r] * w[i] * dis[col[i]]);
        } else {
            int n = i - N_EDGES;
            float d = dis[n];
            fatomic_add(&lc[node_seq[n]], d * d);
        }
    }
    __syncthreads();
    for (int i = threadIdx.x; i < VOCAB; i += TBC)
        gcoeff[blockIdx.x * VOCAB + i] = lc[i];
}

// ---- reduce npart partials, one wave per vocab slot -----------------------
__global__ void __launch_bounds__(256) k_reduce(
        const float* __restrict__ gcoeff, float* __restrict__ coeff, int npart) {
    int g = blockIdx.x * 256 + threadIdx.x;
    int v = g >> 6;
    int l = g & 63;
    if (v >= VOCAB) return;
    float s = 0.0f;
    for (int p = l; p < npart; p += 64) s += gcoeff[p * VOCAB + v];
    for (int off = 32; off > 0; off >>= 1) s += __shfl_down(s, off, 64);
    if (l == 0) coeff[v] = s;
}

// ---- out[d] = (sum_v coeff[v]*(emb@W)[v,d])/N + b[d] ----------------------
__global__ void __launch_bounds__(1024) k_final(
        const float* __restrict__ coeff, const float* __restrict__ emb,
        const float* __restrict__ W, const float* __restrict__ bias,
        float* __restrict__ out) {
    __shared__ float lc[VOCAB];
    __shared__ float tk[16 * 64];
    int t = threadIdx.x;
    for (int v = t; v < VOCAB; v += 1024) lc[v] = coeff[v];
    __syncthreads();

    int k = t & 63;
    int g = t >> 6;
    float p = 0.0f;
    for (int v = g; v < VOCAB; v += 16) p += lc[v] * emb[v * EMB_DIM + k];
    tk[g * 64 + k] = p;
    __syncthreads();

    if (t < 64) {
        float s = 0.0f;
        for (int gg = 0; gg < 16; ++gg) s += tk[gg * 64 + t];
        tk[t] = s;
    }
    __syncthreads();

    if (t < OUT_DIM) {
        float s = 0.0f;
        for (int kk = 0; kk < EMB_DIM; ++kk) s += tk[kk] * W[kk * OUT_DIM + t];
        out[t] = s * (1.0f / (float)N_NODES) + bias[t];
    }
}

extern "C" void kernel_launch(void* const* d_in, const int* in_sizes, int n_in,
                              void* d_out, int out_size, void* d_ws, size_t ws_size,
                              hipStream_t stream) {
    const int*   node_seq = (const int*)  d_in[0];
    const int*   eidx     = (const int*)  d_in[1];   // [2, E] flat
    const float* ew       = (const float*)d_in[2];
    const float* emb      = (const float*)d_in[3];
    const float* W        = (const float*)d_in[4];
    const float* b        = (const float*)d_in[5];
    float*       out      = (float*)d_out;

    const int* row = eidx;
    const int* col = eidx + N_EDGES;

    char* wsb = (char*)d_ws;
    const size_t REC_BYTES = (size_t)NBKT * CAP * sizeof(uint2);  // ~19.3 MB
    const size_t need = REC_BYTES + 4096 + (size_t)N_NODES * 8
                      + (size_t)NBKT * VOCAB * 4 + VOCAB * 4 + 4096;

    if (ws_size >= need) {
        uint2* recs    = (uint2*)wsb;
        int*   cursors = (int*)(wsb + REC_BYTES);
        uint2* disseq  = (uint2*)(wsb + REC_BYTES + 4096);
        float* gcoeff  = (float*)(disseq + N_NODES);
        float* coeff   = gcoeff + (size_t)NBKT * VOCAB;

        k_init<<<1, 256, 0, stream>>>(cursors);
        k_scatter<<<NSB, 256, 0, stream>>>(row, col, ew, cursors, recs);
        k_dis<<<NBKT, 256, 0, stream>>>(recs, cursors, node_seq, disseq);
        k_coeff<<<NBKT, 512, 0, stream>>>(recs, cursors, disseq, gcoeff);
        k_reduce<<<(VOCAB * 64 + 255) / 256, 256, 0, stream>>>(gcoeff, coeff, NBKT);
        k_final<<<1, 1024, 0, stream>>>(coeff, emb, W, b, out);
    } else {
        float* dis    = (float*)wsb;                  // doubles as deg
        float* gcoeff = dis + N_NODES;
        float* coeff  = gcoeff + (size_t)NBC * VOCAB;

        k_init_deg<<<(N_NODES + 255) / 256, 256, 0, stream>>>(dis);
        k_deg<<<(N_EDGES + 255) / 256, 256, 0, stream>>>(col, ew, dis);
        k_dis_fb<<<(N_NODES + 255) / 256, 256, 0, stream>>>(dis);
        k_coeff_stream<<<NBC, TBC, 0, stream>>>(row, col, ew, dis, node_seq, gcoeff);
        k_reduce<<<(VOCAB * 64 + 255) / 256, 256, 0, stream>>>(gcoeff, coeff, NBC);
        k_final<<<1, 1024, 0, stream>>>(coeff, emb, W, b, out);
    }
}